// Round 16
// baseline (244.150 us; speedup 1.0000x reference)
//
#include <hip/hip_runtime.h>

// Problem constants (from reference)
#define NS   1000        // N_SAMPLES
#define NB   32          // batch
#define NK   27          // cluster channels
#define HW   65536       // 256*256
// sim = 10*exp(-cd/1.0 - gd/0.3) + 3*exp(-10*cd)
// SPARSITY (validated R13/R14): coords random in 256^2 => for cd >= 30 sim
// underflows (|masked| <= ~1e-9 << threshold 16.88) => emit exact 0 and skip
// ALL data access for 99.7% of pairs.
// R16: SINGLE FUSED KERNEL — no gather, no ws. Gate from coords (L1); active
// pairs read cluster/guidance rows directly (a-side wave-uniform broadcast,
// b-side scattered). Scattered reads overlap the 128 MB zero/write stream.

#define RA     20          // a-rows per block
#define NCHUNK 50          // NS / RA

__global__ __launch_bounds__(512) void crf_fused(const float* __restrict__ guidance,
                                                 const float* __restrict__ clusters,
                                                 const int* __restrict__ coords,
                                                 float* __restrict__ out) {
    const int bid = blockIdx.x;
    const int n = bid / NCHUNK;
    const int a0 = (bid - n * NCHUNK) * RA;
    const int t = threadIdx.x;

    const int b0 = t;                       // < 1000 always
    const int b1raw = t + 512;
    const int b1 = b1raw < NS ? b1raw : NS - 1;
    const bool w1 = (b1raw < NS);

    // b-side coords/pixels (per-lane, registers)
    const int rb0 = coords[b0], cb0 = coords[NS + b0];
    const int rb1 = coords[b1], cb1 = coords[NS + b1];
    const int pixb0 = rb0 * 256 + cb0;
    const int pixb1 = rb1 * 256 + cb1;
    const float xbr0 = (float)rb0, xbc0 = (float)cb0;
    const float xbr1 = (float)rb1, xbc1 = (float)cb1;

    const float* __restrict__ clN = clusters + (long)n * NK * HW;
    const float* __restrict__ guN = guidance + (long)n * 3 * HW;

    for (int a = 0; a < RA; ++a) {
        const int ai = a0 + a;
        const int ra = coords[ai], ca = coords[NS + ai];   // wave-uniform
        const int pixa = ra * 256 + ca;
        const float xar = (float)ra, xac = (float)ca;
        float* po = out + ((long)n * NS + ai) * NS;

        // ---- slot 0 ----
        {
            float dr = xar - xbr0, dc = xac - xbc0;
            float cd = dr * dr + dc * dc;
            float res = 0.0f;
            if (cd < 30.0f) {
                const float* pa = clN + pixa;
                const float* pb = clN + pixb0;
                float dot = 0.0f;
                #pragma unroll
                for (int k = 0; k < NK; ++k)
                    dot += pa[(long)k * HW] * pb[(long)k * HW];
                const float* qa = guN + pixa;
                const float* qb = guN + pixb0;
                float g0 = qa[0]        - qb[0];
                float g1 = qa[HW]       - qb[HW];
                float g2 = qa[2 * HW]   - qb[2 * HW];
                float gd = g0 * g0 + g1 * g1 + g2 * g2;
                float s = 10.0f * __expf(-cd - gd * (1.0f / 0.3f))
                        +  3.0f * __expf(-10.0f * cd);
                res = -dot * s;
            }
            po[b0] = res;
        }
        // ---- slot 1 ----
        {
            float dr = xar - xbr1, dc = xac - xbc1;
            float cd = dr * dr + dc * dc;
            float res = 0.0f;
            if (w1 && cd < 30.0f) {
                const float* pa = clN + pixa;
                const float* pb = clN + pixb1;
                float dot = 0.0f;
                #pragma unroll
                for (int k = 0; k < NK; ++k)
                    dot += pa[(long)k * HW] * pb[(long)k * HW];
                const float* qa = guN + pixa;
                const float* qb = guN + pixb1;
                float g0 = qa[0]        - qb[0];
                float g1 = qa[HW]       - qb[HW];
                float g2 = qa[2 * HW]   - qb[2 * HW];
                float gd = g0 * g0 + g1 * g1 + g2 * g2;
                float s = 10.0f * __expf(-cd - gd * (1.0f / 0.3f))
                        +  3.0f * __expf(-10.0f * cd);
                res = -dot * s;
            }
            if (w1) po[b1raw] = res;
        }
    }
}

extern "C" void kernel_launch(void* const* d_in, const int* in_sizes, int n_in,
                              void* d_out, int out_size, void* d_ws, size_t ws_size,
                              hipStream_t stream) {
    const float* guidance = (const float*)d_in[0];
    const float* clusters = (const float*)d_in[1];
    const int*   coords   = (const int*)d_in[2];
    float* out = (float*)d_out;

    int blocks = NB * NCHUNK;   // 1600
    crf_fused<<<blocks, 512, 0, stream>>>(guidance, clusters, coords, out);
}

// Round 17
// 56.034 us; speedup vs baseline: 4.3572x; 4.3572x over previous
//
#include <hip/hip_runtime.h>

// Problem constants (from reference)
#define NS   1000        // N_SAMPLES
#define NB   32          // batch
#define NK   27          // cluster channels
#define KP   28          // padded K (for float4)
#define HW   65536       // 256*256
// sim = 10*exp(-cd/1.0 - gd/0.3) + 3*exp(-10*cd)
// SPARSITY (validated R13/R14): cd >= 30 => sim underflows (|masked| <= ~1e-9
// << threshold 16.88) => emit exact 0, skip all data access (99.7% of pairs).
// R17: main stores float4 per thread (4 b-cols) — 4x fewer store uops, 16B/lane.

// ws layout (floats):
//   selc [NB][NS][KP]  : 896000
//   selg [NB][NS][4]   : 128000   (offset 896000)
//   cf   [NS][2]       : 2000     (offset 1024000)
#define OFF_SELG 896000
#define OFF_CF   1024000

typedef __attribute__((ext_vector_type(4))) float f32x4;

// gather: one thread per (n, i, ch), ch in [0,32)  (R10 verbatim)
__global__ void crf_gather(const float* __restrict__ guidance,
                           const float* __restrict__ clusters,
                           const int* __restrict__ coords,
                           float* __restrict__ ws) {
    int tid = blockIdx.x * 256 + threadIdx.x;
    if (tid >= NB * NS * 32) return;
    int ch = tid & 31;
    int ni = tid >> 5;
    int n = ni / NS;
    int i = ni - n * NS;
    int r = coords[i];
    int c = coords[NS + i];
    int pix = r * 256 + c;

    if (ch < KP) {
        float v = 0.0f;
        if (ch < NK)
            v = clusters[((long)n * NK + ch) * HW + pix];
        ws[(long)ni * KP + ch] = v;
    } else {
        int g = ch - KP;  // 0..3
        float v = 0.0f;
        if (g < 3)
            v = guidance[((long)n * 3 + g) * HW + pix];
        ws[OFF_SELG + (long)ni * 4 + g] = v;
        if (g == 3 && n == 0) {
            ws[OFF_CF + i * 2]     = (float)r;
            ws[OFF_CF + i * 2 + 1] = (float)c;
        }
    }
}

#define RA     20          // a-rows per block
#define NCHUNK 50          // NS / RA

// main: block = (n, 20 a-rows); 256 threads; thread t<250 owns b = 4t..4t+3
// and emits ONE float4 store per row. a-row data hoisted (wave-uniform,
// diagonal guarantees >=1 active lane per row); b-side loads lazy in gate.
__global__ __launch_bounds__(256) void crf_main(const float* __restrict__ ws,
                                                float* __restrict__ out) {
    const int bid = blockIdx.x;
    const int n = bid / NCHUNK;
    const int a0 = (bid - n * NCHUNK) * RA;
    const int t = threadIdx.x;

    const float* __restrict__ selc = ws;
    const float* __restrict__ selg = ws + OFF_SELG;
    const float* __restrict__ cf   = ws + OFF_CF;

    const bool act = (t < 250);
    const int b4 = 4 * t;                    // 0..996

    float xbr[4], xbc[4];
    if (act) {
        #pragma unroll
        for (int j = 0; j < 4; ++j) {
            xbr[j] = cf[2 * (b4 + j)];
            xbc[j] = cf[2 * (b4 + j) + 1];
        }
    }

    for (int a = 0; a < RA; ++a) {
        const int ai = a0 + a;
        const long arow = (long)n * NS + ai;
        const float xar = cf[2 * ai], xac = cf[2 * ai + 1];   // uniform

        // uniform a-row data (scalarized by compiler)
        const float4* pa4 = (const float4*)(selc + arow * KP);
        float4 pa[7];
        #pragma unroll
        for (int j = 0; j < 7; ++j) pa[j] = pa4[j];
        const float* pga = selg + arow * 4;
        const float ga0 = pga[0], ga1 = pga[1], ga2 = pga[2];

        if (act) {
            f32x4 res = {0.0f, 0.0f, 0.0f, 0.0f};
            #pragma unroll
            for (int j = 0; j < 4; ++j) {
                float dr = xar - xbr[j], dc = xac - xbc[j];
                float cd = dr * dr + dc * dc;
                if (cd < 30.0f) {
                    const long brow = (long)n * NS + b4 + j;
                    const float4* pb4 = (const float4*)(selc + brow * KP);
                    float dot = 0.0f;
                    #pragma unroll
                    for (int q = 0; q < 7; ++q) {
                        float4 va = pa[q], vb = pb4[q];
                        dot += va.x * vb.x;
                        dot += va.y * vb.y;
                        dot += va.z * vb.z;
                        dot += va.w * vb.w;
                    }
                    const float* pgb = selg + brow * 4;
                    float g0 = ga0 - pgb[0];
                    float g1 = ga1 - pgb[1];
                    float g2 = ga2 - pgb[2];
                    float gd = g0 * g0 + g1 * g1 + g2 * g2;
                    float s = 10.0f * __expf(-cd - gd * (1.0f / 0.3f))
                            +  3.0f * __expf(-10.0f * cd);
                    res[j] = -dot * s;
                }
            }
            *(f32x4*)(out + arow * NS + b4) = res;
        }
    }
}

extern "C" void kernel_launch(void* const* d_in, const int* in_sizes, int n_in,
                              void* d_out, int out_size, void* d_ws, size_t ws_size,
                              hipStream_t stream) {
    const float* guidance = (const float*)d_in[0];
    const float* clusters = (const float*)d_in[1];
    const int*   coords   = (const int*)d_in[2];
    float* out = (float*)d_out;
    float* ws  = (float*)d_ws;

    {
        int total = NB * NS * 32;
        int blocks = (total + 255) / 256;
        crf_gather<<<blocks, 256, 0, stream>>>(guidance, clusters, coords, ws);
    }
    {
        int blocks = NB * NCHUNK;   // 1600
        crf_main<<<blocks, 256, 0, stream>>>(ws, out);
    }
}